// Round 5
// baseline (782.071 us; speedup 1.0000x reference)
//
#include <hip/hip_runtime.h>

// Batched Viterbi decode: B=1024, S=512, T=64.
// R8 (isolation round): R7's dual-chain kernel failed the post-timing
// re-check with no findable source-level bug; the only never-harness-verified
// region was the dual-INTERLEAVED backtrace. R8 keeps the dual-chain FORWARD
// (2 batches/wave, grid 512 -- fills the 1-wave/SIMD latency stalls with the
// other chain's issue) but runs the two backtraces SEQUENTIALLY, each the
// byte-for-byte R5 loop that passed the full harness twice. Pass => dual
// forward sound; fail => dual forward implicated, revert to R5.
// Equality-search backtrace: bptr_s[n*] = first p with
// (vv_{s-1}[p]+feat[s-1][p]) + T[n*,p] == vv_s[n*]; all adds replay forward
// adds bitwise (same association, pk_add == scalar add per component, proven
// by R6's pass), fmax returns an operand bitwise, ballot compares by VALUE,
// so ctz == jnp first-index argmax on ANY input. R4 fallback kept.

typedef float v2f __attribute__((ext_vector_type(2)));

#define B_ 1024
#define S_ 512
#define T_ 64
#define NEGV -10000.0f

// ---------------- R8 fast path: dual forward, sequential verified backtrace ----------------
__global__ __launch_bounds__(64, 1) void viterbi_fwd_bt2(
    const float* __restrict__ feats,   // [B, S, T]
    const float* __restrict__ trans,   // [T, T]
    float* __restrict__ out,           // [B + B*S]
    float* __restrict__ vv)            // workspace [B, S, T]
{
    __shared__ float T_lds[T_ * T_];                 // 16 KB transitions (row-major)
    __shared__ __align__(16) float fvbuf[2][2][T_];  // [chain][parity][tag]

    const int b0 = blockIdx.x * 2;
    const int b1 = b0 + 1;
    const int lane = threadIdx.x;

    // stage transitions into LDS (backtrace row reads)
    {
        const float4* src = reinterpret_cast<const float4*>(trans);
        float4* dst = reinterpret_cast<float4*>(T_lds);
#pragma unroll
        for (int i = 0; i < 16; ++i) dst[i * 64 + lane] = src[i * 64 + lane];
    }

    // transitions row for next = lane, packed as v2f pairs (64 VGPRs)
    v2f t2[32];
#pragma unroll
    for (int p = 0; p < T_; p += 4) {
        const float4 v = *reinterpret_cast<const float4*>(trans + lane * T_ + p);
        t2[p / 2] = v2f{v.x, v.y};
        t2[p / 2 + 1] = v2f{v.z, v.w};
    }
    const float tend = trans[(T_ - 1) * T_ + lane];   // transitions[END][lane]

    float fv0 = (lane == T_ - 2) ? 0.0f : NEGV;       // START = T-2
    float fv1 = fv0;
    fvbuf[0][0][lane] = fv0;
    fvbuf[1][0][lane] = fv1;

    const float* fb0 = feats + (size_t)b0 * S_ * T_ + lane;
    const float* fb1 = feats + (size_t)b1 * S_ * T_ + lane;
    float* vw0 = vv + (size_t)b0 * S_ * T_ + lane;
    float* vw1 = vv + (size_t)b1 * S_ * T_ + lane;

    // feat prefetch rings: 4 steps ahead, per chain
    float fc0[4], fn0[4], fc1[4], fn1[4];
#pragma unroll
    for (int k = 0; k < 4; ++k) {
        fc0[k] = fb0[(size_t)k * T_];
        fc1[k] = fb1[(size_t)k * T_];
    }

#pragma unroll 1
    for (int s4 = 0; s4 < S_ / 4; ++s4) {
#pragma unroll
        for (int k = 0; k < 4; ++k) {
            int sp = 4 * s4 + 4 + k;
            sp = (sp < S_) ? sp : (S_ - 1);
            fn0[k] = fb0[(size_t)sp * T_];
            fn1[k] = fb1[(size_t)sp * T_];
        }
#pragma unroll
        for (int u = 0; u < 4; ++u) {
            const int s = 4 * s4 + u;
            const int rs = s & 1;

            // chain 0: quad broadcast reads + pk_add + max tree
            float g0[16];
#pragma unroll
            for (int j = 0; j < 16; ++j) {
                const float4 q = *reinterpret_cast<const float4*>(&fvbuf[0][rs][4 * j]);
                const v2f a = v2f{q.x, q.y} + t2[2 * j];
                const v2f c = v2f{q.z, q.w} + t2[2 * j + 1];
                g0[j] = fmaxf(fmaxf(a.x, a.y), fmaxf(c.x, c.y));
            }
            // chain 1: same, independent (fills chain 0's stalls)
            float g1[16];
#pragma unroll
            for (int j = 0; j < 16; ++j) {
                const float4 q = *reinterpret_cast<const float4*>(&fvbuf[1][rs][4 * j]);
                const v2f a = v2f{q.x, q.y} + t2[2 * j];
                const v2f c = v2f{q.z, q.w} + t2[2 * j + 1];
                g1[j] = fmaxf(fmaxf(a.x, a.y), fmaxf(c.x, c.y));
            }
#pragma unroll
            for (int off = 8; off >= 1; off >>= 1) {
#pragma unroll
                for (int j = 0; j < off; ++j) {
                    g0[j] = fmaxf(g0[j], g0[j + off]);
                    g1[j] = fmaxf(g1[j], g1[j + off]);
                }
            }
            const float maxv0 = g0[0];
            const float maxv1 = g1[0];

            vw0[(size_t)s * T_] = maxv0;     // exact pre-feat viterbivars
            vw1[(size_t)s * T_] = maxv1;
            fv0 = maxv0 + fc0[u];
            fv1 = maxv1 + fc1[u];
            fvbuf[0][rs ^ 1][lane] = fv0;
            fvbuf[1][rs ^ 1][lane] = fv1;
        }
#pragma unroll
        for (int k = 0; k < 4; ++k) { fc0[k] = fn0[k]; fc1[k] = fn1[k]; }
    }

    // terminal: max/argmax over tags, both chains (butterfly, first-index ties)
    float v0 = fv0 + tend, v1 = fv1 + tend;
    int i0 = lane, i1 = lane;
#pragma unroll
    for (int off = 1; off < 64; off <<= 1) {
        const float vo0 = __shfl_xor(v0, off);
        const int io0 = __shfl_xor(i0, off);
        const float vo1 = __shfl_xor(v1, off);
        const int io1 = __shfl_xor(i1, off);
        const bool t0 = (vo0 > v0) || ((vo0 == v0) && (io0 < i0));
        const bool t1 = (vo1 > v1) || ((vo1 == v1) && (io1 < i1));
        v0 = t0 ? vo0 : v0; i0 = t0 ? io0 : i0;
        v1 = t1 ? vo1 : v1; i1 = t1 ? io1 : i1;
    }
    int ncur0 = __builtin_amdgcn_readfirstlane(i0);
    int ncur1 = __builtin_amdgcn_readfirstlane(i1);
    if (lane == 0) { out[b0] = v0; out[b1] = v1; }

    // ---- backtraces: verbatim R5 single-chain loop, run twice ----
    asm volatile("s_waitcnt vmcnt(0)" ::: "memory");  // vv stores visible to our loads

    // chain 0
    {
        float A = vw0[(size_t)(S_ - 1) * T_];
        float vvR[8], ffR[8];
#pragma unroll
        for (int k = 0; k < 8; ++k) {
            const int s = (S_ - 1) - k;
            vvR[k] = vw0[(size_t)(s - 1) * T_];
            ffR[k] = fb0[(size_t)(s - 1) * T_];
        }
        float emitv = 0.0f;
        float* outp = out + B_ + (size_t)b0 * S_;
        int ncur = ncur0;
#pragma unroll 1
        for (int c = 7; c >= 0; --c) {
#pragma unroll 1
            for (int g = 7; g >= 0; --g) {
                const int base = 64 * c + 8 * g;
#pragma unroll
                for (int kk = 0; kk < 8; ++kk) {
                    const int s = base + 7 - kk;
                    emitv = (lane == (s & 63)) ? (float)ncur : emitv;
                    if (s > 0) {
                        const float target = __int_as_float(
                            __builtin_amdgcn_readlane(__float_as_int(A), ncur));
                        const float trow = T_lds[(ncur << 6) + lane];
                        const float cand = (vvR[kk] + ffR[kk]) + trow;
                        const unsigned long long m = __ballot(cand == target);
                        ncur = ((int)__builtin_ctzll(m)) & 63;
                        A = vvR[kk];
                        const int sp = (s >= 9) ? (s - 9) : 0;
                        vvR[kk] = vw0[(size_t)sp * T_];
                        ffR[kk] = fb0[(size_t)sp * T_];
                    }
                }
            }
            outp[64 * c + lane] = emitv;
        }
    }

    // chain 1
    {
        float A = vw1[(size_t)(S_ - 1) * T_];
        float vvR[8], ffR[8];
#pragma unroll
        for (int k = 0; k < 8; ++k) {
            const int s = (S_ - 1) - k;
            vvR[k] = vw1[(size_t)(s - 1) * T_];
            ffR[k] = fb1[(size_t)(s - 1) * T_];
        }
        float emitv = 0.0f;
        float* outp = out + B_ + (size_t)b1 * S_;
        int ncur = ncur1;
#pragma unroll 1
        for (int c = 7; c >= 0; --c) {
#pragma unroll 1
            for (int g = 7; g >= 0; --g) {
                const int base = 64 * c + 8 * g;
#pragma unroll
                for (int kk = 0; kk < 8; ++kk) {
                    const int s = base + 7 - kk;
                    emitv = (lane == (s & 63)) ? (float)ncur : emitv;
                    if (s > 0) {
                        const float target = __int_as_float(
                            __builtin_amdgcn_readlane(__float_as_int(A), ncur));
                        const float trow = T_lds[(ncur << 6) + lane];
                        const float cand = (vvR[kk] + ffR[kk]) + trow;
                        const unsigned long long m = __ballot(cand == target);
                        ncur = ((int)__builtin_ctzll(m)) & 63;
                        A = vvR[kk];
                        const int sp = (s >= 9) ? (s - 9) : 0;
                        vvR[kk] = vw1[(size_t)sp * T_];
                        ffR[kk] = fb1[(size_t)sp * T_];
                    }
                }
            }
            outp[64 * c + lane] = emitv;
        }
    }
}

// ---------------- R4 fallback (verified; used when workspace too small) ----------------
__global__ __launch_bounds__(64, 1) void viterbi_kernel(
    const float* __restrict__ feats,
    const float* __restrict__ trans,
    float* __restrict__ out)
{
    __shared__ unsigned int bp[S_ / 4][T_];
    __shared__ __align__(16) float fvbuf[2][T_];

    const int b = blockIdx.x;
    const int lane = threadIdx.x;

    float t[T_];
#pragma unroll
    for (int p = 0; p < T_; p += 4) {
        const float4 v = *reinterpret_cast<const float4*>(trans + lane * T_ + p);
        t[p] = v.x; t[p + 1] = v.y; t[p + 2] = v.z; t[p + 3] = v.w;
    }
    const float tend = trans[(T_ - 1) * T_ + lane];

    float fv = (lane == T_ - 2) ? 0.0f : NEGV;
    fvbuf[0][lane] = fv;

    const float* fb = feats + (size_t)b * S_ * T_ + lane;

    float fc[4], fn[4];
#pragma unroll
    for (int k = 0; k < 4; ++k) fc[k] = fb[(size_t)k * T_];

#pragma unroll 1
    for (int s4 = 0; s4 < S_ / 4; ++s4) {
#pragma unroll
        for (int k = 0; k < 4; ++k) {
            int sp = 4 * s4 + 4 + k;
            sp = (sp < S_) ? sp : (S_ - 1);
            fn[k] = fb[(size_t)sp * T_];
        }

        unsigned int pack = 0;
#pragma unroll
        for (int u = 0; u < 4; ++u) {
            const int s = 4 * s4 + u;
            const int rs = s & 1;

            float fvl[T_];
#pragma unroll
            for (int j = 0; j < 16; ++j) {
                const float4 v = *reinterpret_cast<const float4*>(&fvbuf[rs][4 * j]);
                fvl[4 * j] = v.x; fvl[4 * j + 1] = v.y;
                fvl[4 * j + 2] = v.z; fvl[4 * j + 3] = v.w;
            }

            float bv[4]; int bi[4];
#pragma unroll
            for (int g = 0; g < 4; ++g) {
                float bestv = fvl[16 * g] + t[16 * g];
                int besti = 16 * g;
#pragma unroll
                for (int q = 1; q < 16; ++q) {
                    const int p = 16 * g + q;
                    const float c = fvl[p] + t[p];
                    const bool gt = c > bestv;
                    besti = gt ? p : besti;
                    bestv = gt ? c : bestv;
                }
                bv[g] = bestv; bi[g] = besti;
            }
            float BV = bv[0]; int BI = bi[0];
#pragma unroll
            for (int g = 1; g < 4; ++g) {
                const bool gt = bv[g] > BV;
                BI = gt ? bi[g] : BI;
                BV = gt ? bv[g] : BV;
            }

            fv = BV + fc[u];
            fvbuf[rs ^ 1][lane] = fv;
            pack |= ((unsigned int)BI) << (8 * u);
        }
        bp[s4][lane] = pack;

#pragma unroll
        for (int k = 0; k < 4; ++k) fc[k] = fn[k];
    }

    float v = fv + tend;
    int i = lane;
#pragma unroll
    for (int off = 1; off < 64; off <<= 1) {
        const float vo = __shfl_xor(v, off);
        const int io = __shfl_xor(i, off);
        const bool take = (vo > v) || ((vo == v) && (io < i));
        v = take ? vo : v;
        i = take ? io : i;
    }
    int tcur = __builtin_amdgcn_readfirstlane(i);
    if (lane == 0) out[b] = v;

    float* outp = out + B_ + (size_t)b * S_;
#pragma unroll 1
    for (int c = 7; c >= 0; --c) {
        unsigned int wd[16];
#pragma unroll
        for (int j = 0; j < 16; ++j)
            wd[j] = bp[16 * c + j][lane];

        int emit = 0;
#pragma unroll
        for (int k = 63; k >= 0; --k) {
            emit = (lane == k) ? tcur : emit;
            const int word = __builtin_amdgcn_readlane((int)wd[k >> 2], tcur);
            tcur = (word >> (8 * (k & 3))) & 0xff;
        }
        outp[64 * c + lane] = (float)emit;
    }
}

extern "C" void kernel_launch(void* const* d_in, const int* in_sizes, int n_in,
                              void* d_out, int out_size, void* d_ws, size_t ws_size,
                              hipStream_t stream) {
    const float* feats = (const float*)d_in[0];   // [B*S*T] f32
    const float* trans = (const float*)d_in[1];   // [T*T] f32
    float* out = (float*)d_out;                   // [B + B*S] f32

    const size_t need = (size_t)B_ * S_ * T_ * sizeof(float);  // 128 MiB
    if (d_ws != nullptr && ws_size >= need) {
        viterbi_fwd_bt2<<<dim3(B_ / 2), dim3(T_), 0, stream>>>(feats, trans, out, (float*)d_ws);
    } else {
        viterbi_kernel<<<dim3(B_), dim3(T_), 0, stream>>>(feats, trans, out);
    }
}

// Round 6
// 329.026 us; speedup vs baseline: 2.3769x; 2.3769x over previous
//
#include <hip/hip_runtime.h>

// Batched Viterbi decode: B=1024, S=512, T=64.
// R9: restore the twice-verified R5 structure (single chain/wave, grid 1024;
// value-only fmax-tree forward + equality-search backtrace) with ONE minimal
// edit: the per-step vw global store is buffered in registers and issued once
// per 4-step body, moving store-related vmcnt waits OFF the recurrence chain.
// Same values, same addresses, same layout; backtrace byte-identical to R5.
// Lesson from R6/R7/R8: at 1 wave/SIMD, wall time == per-batch dependency
// chain; multi-chain packing can't shorten it, and v2f/dual-pressure hits a
// register-allocator cliff (VGPR 68, remat storm, 3.5x). Attack the chain.
// Equality backtrace: bptr_s[n*] = first p with
// (vv_{s-1}[p]+feat[s-1][p]) + T[n*,p] == vv_s[n*]; adds replay forward adds
// bitwise, fmax returns an operand bitwise, ballot compares by VALUE, so
// ctz(ballot) == jnp first-index argmax on any input. R4 fallback kept.

#define B_ 1024
#define S_ 512
#define T_ 64
#define NEGV -10000.0f

// ---------------- R9 fast path ----------------
__global__ __launch_bounds__(64, 1) void viterbi_fwd_bt(
    const float* __restrict__ feats,   // [B, S, T]
    const float* __restrict__ trans,   // [T, T]
    float* __restrict__ out,           // [B + B*S]
    float* __restrict__ vv)            // workspace [B, S, T]: pre-feat max per step
{
    __shared__ float T_lds[T_ * T_];              // 16 KB transitions copy (row-major)
    __shared__ __align__(16) float fvbuf[2][T_];  // parity-double-buffered fv

    const int b = blockIdx.x;
    const int lane = threadIdx.x;      // forward: lane = next tag; backtrace: lane = prev tag

    // stage transitions into LDS for backtrace row reads (coalesced float4)
    {
        const float4* src = reinterpret_cast<const float4*>(trans);
        float4* dst = reinterpret_cast<float4*>(T_lds);
#pragma unroll
        for (int i = 0; i < 16; ++i) dst[i * 64 + lane] = src[i * 64 + lane];
    }

    // transitions row for next = lane
    float t[T_];
#pragma unroll
    for (int p = 0; p < T_; p += 4) {
        const float4 v = *reinterpret_cast<const float4*>(trans + lane * T_ + p);
        t[p] = v.x; t[p + 1] = v.y; t[p + 2] = v.z; t[p + 3] = v.w;
    }
    const float tend = trans[(T_ - 1) * T_ + lane];   // transitions[END][lane]

    float fv = (lane == T_ - 2) ? 0.0f : NEGV;        // START = T-2
    fvbuf[0][lane] = fv;

    const float* fb = feats + (size_t)b * S_ * T_ + lane;
    float* vw = vv + (size_t)b * S_ * T_ + lane;

    // feat prefetch ring: 4 steps ahead
    float fc[4], fn[4];
#pragma unroll
    for (int k = 0; k < 4; ++k) fc[k] = fb[(size_t)k * T_];

#pragma unroll 1
    for (int s4 = 0; s4 < S_ / 4; ++s4) {
#pragma unroll
        for (int k = 0; k < 4; ++k) {
            int sp = 4 * s4 + 4 + k;
            sp = (sp < S_) ? sp : (S_ - 1);
            fn[k] = fb[(size_t)sp * T_];
        }

        float mv[4];                      // buffered step-maxes (stores issued after body)
#pragma unroll
        for (int u = 0; u < 4; ++u) {
            const int s = 4 * s4 + u;
            const int rs = s & 1;
            // 64 candidates: add + fmax tree (no argmax tracking)
            float gm[16];
#pragma unroll
            for (int j = 0; j < 16; ++j) {
                const float4 v = *reinterpret_cast<const float4*>(&fvbuf[rs][4 * j]);
                const float c0 = v.x + t[4 * j];
                const float c1 = v.y + t[4 * j + 1];
                const float c2 = v.z + t[4 * j + 2];
                const float c3 = v.w + t[4 * j + 3];
                gm[j] = fmaxf(fmaxf(c0, c1), fmaxf(c2, c3));
            }
#pragma unroll
            for (int off = 8; off >= 1; off >>= 1)
#pragma unroll
                for (int j = 0; j < off; ++j) gm[j] = fmaxf(gm[j], gm[j + off]);
            const float maxv = gm[0];

            mv[u] = maxv;                 // defer the global store (off the chain)
            fv = maxv + fc[u];
            fvbuf[rs ^ 1][lane] = fv;
        }

        // issue the 4 deferred vw stores (same addresses/values as per-step R5)
#pragma unroll
        for (int u = 0; u < 4; ++u)
            vw[(size_t)(4 * s4 + u) * T_] = mv[u];

#pragma unroll
        for (int k = 0; k < 4; ++k) fc[k] = fn[k];
    }

    // terminal: max/argmax over tags (butterfly, first-index ties)
    float v = fv + tend;
    int i = lane;
#pragma unroll
    for (int off = 1; off < 64; off <<= 1) {
        const float vo = __shfl_xor(v, off);
        const int io = __shfl_xor(i, off);
        const bool take = (vo > v) || ((vo == v) && (io < i));
        v = take ? vo : v;
        i = take ? io : i;
    }
    int ncur = __builtin_amdgcn_readfirstlane(i);
    if (lane == 0) out[b] = v;

    // ---- backtrace: equality search, 1 ballot per step (verbatim R5) ----
    asm volatile("s_waitcnt vmcnt(0)" ::: "memory");  // vv stores visible to our loads

    float A = vw[(size_t)(S_ - 1) * T_];              // vv_511 vector (lane p holds [p])
    float vvR[8], ffR[8];
#pragma unroll
    for (int k = 0; k < 8; ++k) {
        const int s = (S_ - 1) - k;
        vvR[k] = vw[(size_t)(s - 1) * T_];
        ffR[k] = fb[(size_t)(s - 1) * T_];
    }

    float emitv = 0.0f;
    float* outp = out + B_ + (size_t)b * S_;

#pragma unroll 1
    for (int c = 7; c >= 0; --c) {
#pragma unroll 1
        for (int g = 7; g >= 0; --g) {
            const int base = 64 * c + 8 * g;
#pragma unroll
            for (int kk = 0; kk < 8; ++kk) {
                const int s = base + 7 - kk;
                emitv = (lane == (s & 63)) ? (float)ncur : emitv;
                if (s > 0) {
                    const float target = __int_as_float(
                        __builtin_amdgcn_readlane(__float_as_int(A), ncur));
                    const float trow = T_lds[(ncur << 6) + lane];
                    const float cand = (vvR[kk] + ffR[kk]) + trow;
                    const unsigned long long m = __ballot(cand == target);
                    ncur = ((int)__builtin_ctzll(m)) & 63;   // first p == first-index argmax
                    A = vvR[kk];
                    const int sp = (s >= 9) ? (s - 9) : 0;
                    vvR[kk] = vw[(size_t)sp * T_];
                    ffR[kk] = fb[(size_t)sp * T_];
                }
            }
        }
        outp[64 * c + lane] = emitv;   // coalesced 256B store per chunk
    }
}

// ---------------- R4 fallback (verified; used when workspace too small) ----------------
__global__ __launch_bounds__(64, 1) void viterbi_kernel(
    const float* __restrict__ feats,
    const float* __restrict__ trans,
    float* __restrict__ out)
{
    __shared__ unsigned int bp[S_ / 4][T_];
    __shared__ __align__(16) float fvbuf[2][T_];

    const int b = blockIdx.x;
    const int lane = threadIdx.x;

    float t[T_];
#pragma unroll
    for (int p = 0; p < T_; p += 4) {
        const float4 v = *reinterpret_cast<const float4*>(trans + lane * T_ + p);
        t[p] = v.x; t[p + 1] = v.y; t[p + 2] = v.z; t[p + 3] = v.w;
    }
    const float tend = trans[(T_ - 1) * T_ + lane];

    float fv = (lane == T_ - 2) ? 0.0f : NEGV;
    fvbuf[0][lane] = fv;

    const float* fb = feats + (size_t)b * S_ * T_ + lane;

    float fc[4], fn[4];
#pragma unroll
    for (int k = 0; k < 4; ++k) fc[k] = fb[(size_t)k * T_];

#pragma unroll 1
    for (int s4 = 0; s4 < S_ / 4; ++s4) {
#pragma unroll
        for (int k = 0; k < 4; ++k) {
            int sp = 4 * s4 + 4 + k;
            sp = (sp < S_) ? sp : (S_ - 1);
            fn[k] = fb[(size_t)sp * T_];
        }

        unsigned int pack = 0;
#pragma unroll
        for (int u = 0; u < 4; ++u) {
            const int s = 4 * s4 + u;
            const int rs = s & 1;

            float fvl[T_];
#pragma unroll
            for (int j = 0; j < 16; ++j) {
                const float4 v = *reinterpret_cast<const float4*>(&fvbuf[rs][4 * j]);
                fvl[4 * j] = v.x; fvl[4 * j + 1] = v.y;
                fvl[4 * j + 2] = v.z; fvl[4 * j + 3] = v.w;
            }

            float bv[4]; int bi[4];
#pragma unroll
            for (int g = 0; g < 4; ++g) {
                float bestv = fvl[16 * g] + t[16 * g];
                int besti = 16 * g;
#pragma unroll
                for (int q = 1; q < 16; ++q) {
                    const int p = 16 * g + q;
                    const float c = fvl[p] + t[p];
                    const bool gt = c > bestv;
                    besti = gt ? p : besti;
                    bestv = gt ? c : bestv;
                }
                bv[g] = bestv; bi[g] = besti;
            }
            float BV = bv[0]; int BI = bi[0];
#pragma unroll
            for (int g = 1; g < 4; ++g) {
                const bool gt = bv[g] > BV;
                BI = gt ? bi[g] : BI;
                BV = gt ? bv[g] : BV;
            }

            fv = BV + fc[u];
            fvbuf[rs ^ 1][lane] = fv;
            pack |= ((unsigned int)BI) << (8 * u);
        }
        bp[s4][lane] = pack;

#pragma unroll
        for (int k = 0; k < 4; ++k) fc[k] = fn[k];
    }

    float v = fv + tend;
    int i = lane;
#pragma unroll
    for (int off = 1; off < 64; off <<= 1) {
        const float vo = __shfl_xor(v, off);
        const int io = __shfl_xor(i, off);
        const bool take = (vo > v) || ((vo == v) && (io < i));
        v = take ? vo : v;
        i = take ? io : i;
    }
    int tcur = __builtin_amdgcn_readfirstlane(i);
    if (lane == 0) out[b] = v;

    float* outp = out + B_ + (size_t)b * S_;
#pragma unroll 1
    for (int c = 7; c >= 0; --c) {
        unsigned int wd[16];
#pragma unroll
        for (int j = 0; j < 16; ++j)
            wd[j] = bp[16 * c + j][lane];

        int emit = 0;
#pragma unroll
        for (int k = 63; k >= 0; --k) {
            emit = (lane == k) ? tcur : emit;
            const int word = __builtin_amdgcn_readlane((int)wd[k >> 2], tcur);
            tcur = (word >> (8 * (k & 3))) & 0xff;
        }
        outp[64 * c + lane] = (float)emit;
    }
}

extern "C" void kernel_launch(void* const* d_in, const int* in_sizes, int n_in,
                              void* d_out, int out_size, void* d_ws, size_t ws_size,
                              hipStream_t stream) {
    const float* feats = (const float*)d_in[0];   // [B*S*T] f32
    const float* trans = (const float*)d_in[1];   // [T*T] f32
    float* out = (float*)d_out;                   // [B + B*S] f32

    const size_t need = (size_t)B_ * S_ * T_ * sizeof(float);  // 128 MiB
    if (d_ws != nullptr && ws_size >= need) {
        viterbi_fwd_bt<<<dim3(B_), dim3(T_), 0, stream>>>(feats, trans, out, (float*)d_ws);
    } else {
        viterbi_kernel<<<dim3(B_), dim3(T_), 0, stream>>>(feats, trans, out);
    }
}